// Round 2
// baseline (262.244 us; speedup 1.0000x reference)
//
#include <hip/hip_runtime.h>
#include <hip/hip_bf16.h>

// Problem: B=8, T=4096, D=64, K=1024. N = B*T = 32768 rows.
// Inputs:  d_in[0] = x (f32, 2097152), d_in[1] = embeddings (f32, [D][K] = 64x1024)
// Output: FLOAT32, concatenated in return order:
//   quantized (2097152) | encodings (33554432) | indices (32768) | loss (1)

#define NROWS 32768
#define DDIM 64
#define KCB 1024

// ws layout (float index):
#define WS_ET    0         // Et [K][D] transposed embeddings (65536 f32)
#define WS_H     65536     // 0.5*||e_k||^2 (1024)
#define WS_LACC  66560     // loss accumulator (1)
#define WS_PBEST 66564     // per-(quarter,row) best score (4*32768)
#define WS_PIDX  197636    // per-(quarter,row) best index (4*32768 int)
#define WS_IBEST 328708    // final index per row (32768 int)

// K1: transpose E (D,K) -> Et (K,D), h[k] = 0.5*sum_d e[d][k]^2, zero loss acc.
__global__ __launch_bounds__(256) void k1_prep(const float* __restrict__ E,
                                               float* __restrict__ Et,
                                               float* __restrict__ h,
                                               float* __restrict__ lacc) {
  int k = blockIdx.x * 256 + threadIdx.x;   // 0..1023
  float col[DDIM];
  float sum = 0.f;
#pragma unroll
  for (int d = 0; d < DDIM; ++d) {
    float v = E[d * KCB + k];               // coalesced across lanes
    col[d] = v;
    sum = fmaf(v, v, sum);
  }
  float4* dst = (float4*)(Et + (size_t)k * DDIM);
#pragma unroll
  for (int i = 0; i < 16; ++i)
    dst[i] = make_float4(col[4*i], col[4*i+1], col[4*i+2], col[4*i+3]);
  h[k] = 0.5f * sum;
  if (k == 0) lacc[0] = 0.f;
}

// K2: per (row, K-quarter) partial argmax of score = x.e_k - 0.5||e_k||^2
// (argmax of score == argmin of squared distance; ||x||^2 is row-constant)
__global__ __launch_bounds__(256) void k2_score(const float* __restrict__ x,
                                                const float* __restrict__ Et,
                                                const float* __restrict__ h,
                                                float* __restrict__ pbest,
                                                int* __restrict__ pidx) {
  int bid = blockIdx.x;           // 0..511
  int kq  = bid & 3;              // K quarter
  int n   = (bid >> 2) * 256 + threadIdx.x;

  const float4* xr = (const float4*)(x + (size_t)n * DDIM);
  float4 xv[16];
#pragma unroll
  for (int i = 0; i < 16; ++i) xv[i] = xr[i];

  const float4* Ef4 = (const float4*)Et;
  int kbase = kq * 256;
  float best = -3.0e38f;
  int besti = kbase;

  for (int k0 = kbase; k0 < kbase + 256; k0 += 8) {
    float acc[8];
#pragma unroll
    for (int j = 0; j < 8; ++j) acc[j] = -h[k0 + j];
#pragma unroll
    for (int i = 0; i < 16; ++i) {
      float4 xi = xv[i];
#pragma unroll
      for (int j = 0; j < 8; ++j) {
        float4 e4 = Ef4[(k0 + j) * 16 + i];   // wave-uniform -> scalar loads
        acc[j] = fmaf(xi.x, e4.x, acc[j]);
        acc[j] = fmaf(xi.y, e4.y, acc[j]);
        acc[j] = fmaf(xi.z, e4.z, acc[j]);
        acc[j] = fmaf(xi.w, e4.w, acc[j]);
      }
    }
#pragma unroll
    for (int j = 0; j < 8; ++j) {
      if (acc[j] > best) { best = acc[j]; besti = k0 + j; }  // strict >: first max wins
    }
  }
  pbest[kq * NROWS + n] = best;
  pidx [kq * NROWS + n] = besti;
}

// K3: combine quarters, write indices (f32) + quantized (f32), accumulate loss.
__global__ __launch_bounds__(256) void k3_finalize(const float* __restrict__ x,
                                                   const float* __restrict__ Et,
                                                   const float* __restrict__ pbest,
                                                   const int* __restrict__ pidx,
                                                   float* __restrict__ lacc,
                                                   int* __restrict__ ibest,
                                                   float* __restrict__ out_q,
                                                   float* __restrict__ out_ind) {
  int n = blockIdx.x * 256 + threadIdx.x;
  float best = pbest[n];
  int bi = pidx[n];
#pragma unroll
  for (int q = 1; q < 4; ++q) {               // ascending quarters: first-occurrence ties
    float b = pbest[q * NROWS + n];
    int i2 = pidx[q * NROWS + n];
    if (b > best) { best = b; bi = i2; }
  }
  ibest[n] = bi;
  out_ind[n] = (float)bi;

  const float4* xr = (const float4*)(x + (size_t)n * DDIM);
  const float4* qr = (const float4*)(Et + (size_t)bi * DDIM);
  float lsum = 0.f;
#pragma unroll
  for (int i = 0; i < 16; ++i) {
    float4 q4 = qr[i];
    float4 x4 = xr[i];
    float d0 = q4.x - x4.x, d1 = q4.y - x4.y, d2 = q4.z - x4.z, d3 = q4.w - x4.w;
    lsum = fmaf(d0, d0, lsum); lsum = fmaf(d1, d1, lsum);
    lsum = fmaf(d2, d2, lsum); lsum = fmaf(d3, d3, lsum);
    *(float4*)(out_q + (size_t)n * DDIM + i * 4) = q4;
  }

  // loss reduction: wave shfl -> LDS -> one atomic per block
#pragma unroll
  for (int off = 32; off > 0; off >>= 1) lsum += __shfl_down(lsum, off);
  __shared__ float red[4];
  int lane = threadIdx.x & 63, w = threadIdx.x >> 6;
  if (lane == 0) red[w] = lsum;
  __syncthreads();
  if (threadIdx.x == 0) atomicAdd(lacc, red[0] + red[1] + red[2] + red[3]);
}

// K4: streaming one-hot encodings writer (f32). Thread t covers cols [4t, 4t+4).
__global__ __launch_bounds__(256) void k4_enc(const int* __restrict__ ibest,
                                              float* __restrict__ out_enc) {
  int t = threadIdx.x;
  int r0 = blockIdx.x * 16;
#pragma unroll
  for (int r = 0; r < 16; ++r) {
    int row = r0 + r;
    int bk = ibest[row];              // wave-uniform broadcast
    bool hit = (bk >> 2) == t;
    int j = bk & 3;
    float4 v;
    v.x = (hit && j == 0) ? 1.0f : 0.0f;
    v.y = (hit && j == 1) ? 1.0f : 0.0f;
    v.z = (hit && j == 2) ? 1.0f : 0.0f;
    v.w = (hit && j == 3) ? 1.0f : 0.0f;
    *(float4*)(out_enc + (size_t)row * KCB + t * 4) = v;
  }
}

// K5: finalize loss
__global__ void k5_loss(const float* __restrict__ lacc, float* __restrict__ out_loss) {
  out_loss[0] = lacc[0] * (1.0f / 2097152.0f);
}

extern "C" void kernel_launch(void* const* d_in, const int* in_sizes, int n_in,
                              void* d_out, int out_size, void* d_ws, size_t ws_size,
                              hipStream_t stream) {
  const float* x = (const float*)d_in[0];
  const float* E = (const float*)d_in[1];

  float* ws    = (float*)d_ws;
  float* Et    = ws + WS_ET;
  float* h     = ws + WS_H;
  float* lacc  = ws + WS_LACC;
  float* pbest = ws + WS_PBEST;
  int*   pidx  = (int*)(ws + WS_PIDX);
  int*   ibest = (int*)(ws + WS_IBEST);

  float* out      = (float*)d_out;
  float* out_q    = out;                      // 2097152
  float* out_enc  = out + 2097152;            // 33554432
  float* out_ind  = out + 35651584;           // 32768
  float* out_loss = out + 35684352;           // 1

  k1_prep<<<4, 256, 0, stream>>>(E, Et, h, lacc);
  k2_score<<<512, 256, 0, stream>>>(x, Et, h, pbest, pidx);
  k3_finalize<<<128, 256, 0, stream>>>(x, Et, pbest, pidx, lacc, ibest, out_q, out_ind);
  k4_enc<<<2048, 256, 0, stream>>>(ibest, out_enc);
  k5_loss<<<1, 1, 0, stream>>>(lacc, out_loss);
}